// Round 12
// baseline (271.686 us; speedup 1.0000x reference)
//
#include <hip/hip_runtime.h>

typedef short bh8 __attribute__((ext_vector_type(8)));
typedef short bh4 __attribute__((ext_vector_type(4)));
typedef float f4 __attribute__((ext_vector_type(4)));
typedef unsigned int u32;
typedef u32 u32x2 __attribute__((ext_vector_type(2)));
typedef u32 u32x4 __attribute__((ext_vector_type(4)));

#if __has_builtin(__builtin_amdgcn_exp2f)
#define EXP2(x) __builtin_amdgcn_exp2f(x)
#else
#define EXP2(x) exp2f(x)
#endif

__device__ __forceinline__ short f2bf(float f) {
  unsigned u = __float_as_uint(f);
  u += 0x7FFFu + ((u >> 16) & 1u);
  return (short)(u >> 16);
}

__device__ __forceinline__ void async16(const void* g, void* l) {
  __builtin_amdgcn_global_load_lds((const __attribute__((address_space(1))) void*)g,
                                   (__attribute__((address_space(3))) void*)l, 16, 0, 0);
}

// ---------------- fused fp32 -> bf16 convert: x + Wq,Wk,Wv,Wo in ONE launch ----------------
__global__ void cvt_all(const float* __restrict__ x, const float* __restrict__ Wq,
                        const float* __restrict__ Wk, const float* __restrict__ Wv,
                        const float* __restrict__ Wo, short* __restrict__ xb,
                        short* __restrict__ wqb) {
  int i = blockIdx.x * blockDim.x + threadIdx.x;
  const float* src;
  short* dst;
  int idx;
  if (i < (1 << 21)) {
    src = x; dst = xb; idx = i;
  } else {
    int j = i - (1 << 21);
    int w = j >> 18;
    idx = j & ((1 << 18) - 1);
    src = w == 0 ? Wq : w == 1 ? Wk : w == 2 ? Wv : Wo;
    dst = wqb + ((size_t)w << 20);
  }
  f4 v = *(const f4*)(src + (size_t)idx * 4);
  bh4 o;
  o[0] = f2bf(v[0]); o[1] = f2bf(v[1]); o[2] = f2bf(v[2]); o[3] = f2bf(v[3]);
  *(bh4*)(dst + (size_t)idx * 4) = o;
}

// ---------------- fused Q/K/V^T projection (256x128 tile, BK=64, 8 waves) ----------------
// r12: scale the PROVEN structure (session record: parameter changes inside it 3/3 wins,
// sync rewrites 0/3). Per-wave code is byte-equivalent to r11's gemm_body (acc[4][4],
// af/bfr[4], chunk-XOR swizzle, 2-barrier BK=64 loop, VGPR=64); block = 256x128 with 8
// waves (2x2 of 64x64). Blocks 1536 -> 768 = 3/CU (LDS 48KB x3 = 144KB). Staged bytes
// /step/CU 192->144KB (-25%); FLOP/staged-byte 65->87 (+33%); drain events halve.
// Standalone kernel (rule #19: no shared templates with bt).
// XCD clustering (bijective, 768%8==0): each XCD owns x rows xcd*1024..+1023 for BOTH
// paths -- Q/K: 4 A-panels of 256 rows; V^T: 8 B-panels of 128 rows. x L2-resident.
__global__ __launch_bounds__(512) void gemm_qkv(const short* __restrict__ xb,
                                                const short* __restrict__ W3,
                                                const float* __restrict__ bq,
                                                const float* __restrict__ bk,
                                                const float* __restrict__ bv,
                                                short* __restrict__ Qo, short* __restrict__ Ko,
                                                short* __restrict__ VTo, float qscale) {
  __shared__ __align__(16) short a_lds[256 * 64];  // 32KB
  __shared__ __align__(16) short b_lds[128 * 64];  // 16KB
  const int t = threadIdx.x;
  const int lane = t & 63, wave = t >> 6, quad = lane >> 4, l15 = lane & 15;
  const int mw = (wave >> 1) * 64, nw = (wave & 1) * 64;

  const int linear = blockIdx.x;
  const int xcd = linear & 7;
  const int slot = linear >> 3;  // 0..95
  const short* A;
  const short* B;
  const float* bias;
  short* C;
  float scale = 1.0f;
  int m0, n0, N;
  bool brow;
  if (slot < 64) {
    // Q (which=0) / K (which=1): C[m][n] = x[m] . W[n] ; A=x, B=W
    int byp = xcd * 4 + (slot >> 4);  // x row-panel (256 rows) cluster per XCD
    int r = slot & 15;
    int which = r >> 3;
    int nx = r & 7;
    m0 = byp * 256;
    n0 = nx * 128;
    A = xb;
    B = W3 + (size_t)which * 1024 * 1024;
    bias = which == 0 ? bq : bk;
    C = which == 0 ? Qo : Ko;
    scale = which == 0 ? qscale : 1.0f;
    N = 1024;
    brow = false;
  } else {
    // V^T: C[m][n] = Wv[m] . x[n] ; A=Wv, B=x
    int s2 = slot - 64;               // 0..31
    int nloc = s2 >> 2, mv = s2 & 3;  // x row-panel (128 rows) cluster per XCD
    m0 = mv * 256;
    n0 = (xcd * 8 + nloc) * 128;
    A = W3 + (size_t)2 * 1024 * 1024;
    B = xb;
    bias = bv;
    C = VTo;
    N = 8192;
    brow = true;
  }

  f4 acc[4][4];
#pragma unroll
  for (int i = 0; i < 4; ++i)
#pragma unroll
    for (int j = 0; j < 4; ++j) acc[i][j] = (f4){0.f, 0.f, 0.f, 0.f};

  for (int k0 = 0; k0 < 1024; k0 += 64) {
    __syncthreads();  // prior step's LDS reads done
    // stage A tile [256][64]: 2048 chunks / 512 threads = 4 each
#pragma unroll
    for (int i = 0; i < 4; ++i) {
      int c = i * 512 + t;
      int m = c >> 3;
      int kq = (c & 7) ^ (m & 7);
      async16(A + (size_t)(m0 + m) * 1024 + k0 + kq * 8, (char*)a_lds + c * 16);
    }
    // stage B tile [128][64]: 1024 chunks / 512 threads = 2 each
#pragma unroll
    for (int i = 0; i < 2; ++i) {
      int c = i * 512 + t;
      int m = c >> 3;
      int kq = (c & 7) ^ (m & 7);
      async16(B + (size_t)(n0 + m) * 1024 + k0 + kq * 8, (char*)b_lds + c * 16);
    }
    __syncthreads();  // staging complete (drains vmcnt)

#pragma unroll
    for (int s = 0; s < 2; ++s) {
      bh8 af[4], bfr[4];
#pragma unroll
      for (int ms = 0; ms < 4; ++ms) {
        int m = mw + ms * 16 + l15;
        int pos = m * 8 + ((s * 4 + quad) ^ (m & 7));
        af[ms] = *(const bh8*)(a_lds + pos * 8);
      }
#pragma unroll
      for (int ns = 0; ns < 4; ++ns) {
        int n = nw + ns * 16 + l15;
        int pos = n * 8 + ((s * 4 + quad) ^ (n & 7));
        bfr[ns] = *(const bh8*)(b_lds + pos * 8);
      }
#pragma unroll
      for (int ms = 0; ms < 4; ++ms)
#pragma unroll
        for (int ns = 0; ns < 4; ++ns)
          acc[ms][ns] = __builtin_amdgcn_mfma_f32_16x16x32_bf16(af[ms], bfr[ns], acc[ms][ns], 0, 0, 0);
    }
  }
#pragma unroll
  for (int ns = 0; ns < 4; ++ns) {
    int col = n0 + nw + ns * 16 + l15;
    float bcol = brow ? 0.f : bias[col & 1023];
#pragma unroll
    for (int ms = 0; ms < 4; ++ms) {
      int row = m0 + mw + ms * 16 + quad * 4;
#pragma unroll
      for (int r = 0; r < 4; ++r) {
        float bv_ = brow ? bias[(row + r) & 1023] : bcol;
        float v = (acc[ms][ns][r] + bv_) * scale;
        C[(size_t)(row + r) * N + col] = f2bf(v);
      }
    }
  }
}

// ---------------- out-projection (standalone, 128x64 tile, BK=64, 4 waves) ----------------
// r11 form kept byte-identical this round (single-variable attribution; r12 targets qkv).
__global__ void gemm_bt_f32(const short* __restrict__ A, const short* __restrict__ Bw,
                            const float* __restrict__ bias, float* __restrict__ C) {
  __shared__ __align__(16) short a_lds[128 * 64];
  __shared__ __align__(16) short b_lds[64 * 64];
  const int t = threadIdx.x;
  const int lane = t & 63, wave = t >> 6, quad = lane >> 4, l15 = lane & 15;
  const int mw = (wave >> 1) * 64, nw = (wave & 1) * 32;
  const int linear = blockIdx.y * 16 + blockIdx.x;
  const int xcd = linear & 7;
  const int slot = linear >> 3;               // 0..127
  const int m0 = (xcd * 8 + (slot >> 4)) * 128;  // A row-panel cluster per XCD
  const int n0 = (slot & 15) * 64;

  f4 acc[4][2];
#pragma unroll
  for (int i = 0; i < 4; ++i)
#pragma unroll
    for (int j = 0; j < 2; ++j) acc[i][j] = (f4){0.f, 0.f, 0.f, 0.f};

  for (int k0 = 0; k0 < 1024; k0 += 64) {
    __syncthreads();
    // stage A tile [128][64]
#pragma unroll
    for (int i = 0; i < 4; ++i) {
      int c = i * 256 + t;
      int m = c >> 3;
      int kq = (c & 7) ^ (m & 7);
      async16(A + (size_t)(m0 + m) * 1024 + k0 + kq * 8, (char*)a_lds + c * 16);
    }
    // stage B tile [64][64]
#pragma unroll
    for (int i = 0; i < 2; ++i) {
      int c = i * 256 + t;
      int m = c >> 3;
      int kq = (c & 7) ^ (m & 7);
      async16(Bw + (size_t)(n0 + m) * 1024 + k0 + kq * 8, (char*)b_lds + c * 16);
    }
    __syncthreads();

#pragma unroll
    for (int s = 0; s < 2; ++s) {
      bh8 af[4], bfr[2];
#pragma unroll
      for (int ms = 0; ms < 4; ++ms) {
        int m = mw + ms * 16 + l15;
        int pos = m * 8 + ((s * 4 + quad) ^ (m & 7));
        af[ms] = *(const bh8*)(a_lds + pos * 8);
      }
#pragma unroll
      for (int ns = 0; ns < 2; ++ns) {
        int n = nw + ns * 16 + l15;
        int pos = n * 8 + ((s * 4 + quad) ^ (n & 7));
        bfr[ns] = *(const bh8*)(b_lds + pos * 8);
      }
#pragma unroll
      for (int ms = 0; ms < 4; ++ms)
#pragma unroll
        for (int ns = 0; ns < 2; ++ns)
          acc[ms][ns] = __builtin_amdgcn_mfma_f32_16x16x32_bf16(af[ms], bfr[ns], acc[ms][ns], 0, 0, 0);
    }
  }
#pragma unroll
  for (int ns = 0; ns < 2; ++ns) {
    int col = n0 + nw + ns * 16 + l15;
    float bcol = bias[col & 1023];
#pragma unroll
    for (int ms = 0; ms < 4; ++ms) {
      int row = m0 + mw + ms * 16 + quad * 4;
#pragma unroll
      for (int r = 0; r < 4; ++r)
        C[(size_t)(row + r) * 1024 + col] = acc[ms][ns][r] + bcol;
    }
  }
}

// ---------------- Flash attention (S^T formulation, static softmax bound) ----------------
// r12 = r9/r11 exactly (85.7us: single-buffer 2-barrier, permlane P-redistribution,
// conflicts 0, XCD head clustering FETCH 24.6MB; MFMA+VALU ~85% joint SIMD issue).
__global__ void attn_kernel(const short* __restrict__ Qb, const short* __restrict__ Kb,
                            const short* __restrict__ VTb, short* __restrict__ AO) {
  __shared__ __align__(16) short k_lds[64 * 64];     // K tile, xor-chunk swizzled [key][d]
  __shared__ __align__(16) short vt_lds[64 * 64];    // V^T tile, xor-chunk swizzled [d][key]
  const int t = threadIdx.x, lane = t & 63, wave = t >> 6, quad = lane >> 4, l15 = lane & 15;
  const int linear = blockIdx.y * 16 + blockIdx.x;
  const int xcd = linear & 7;
  const int slot = linear >> 3;            // 0..127
  const int bh = xcd * 8 + (slot >> 4);    // head clustering: 8 heads per XCD
  const int qx = slot & 15;
  const int b = bh >> 4, h = bh & 15;
  const int q0 = qx * 128;
  const size_t baseq = ((size_t)b * 2048) * 1024 + (size_t)h * 64;
  const size_t basev = ((size_t)h * 64) * 8192 + (size_t)b * 2048;

  // Q fragments in registers (B-operand: n=l15 -> q, k=quad*8+j -> d)
  bh8 qf[2][2];
#pragma unroll
  for (int mi = 0; mi < 2; ++mi)
#pragma unroll
    for (int ks = 0; ks < 2; ++ks)
      qf[mi][ks] = *(const bh8*)(Qb + baseq + (size_t)(q0 + wave * 32 + mi * 16 + l15) * 1024 + ks * 32 + quad * 8);

  f4 O[2][4];
  float l_part[2] = {0.f, 0.f};
#pragma unroll
  for (int mi = 0; mi < 2; ++mi)
#pragma unroll
    for (int di = 0; di < 4; ++di) O[mi][di] = (f4){0.f, 0.f, 0.f, 0.f};

  for (int kt = 0; kt < 2048; kt += 64) {
    __syncthreads();  // prior tile's LDS reads done
    // stage K tile: chunk c -> (kk=c>>3, dq=(c&7)^(kk&7))
#pragma unroll
    for (int i = 0; i < 2; ++i) {
      int c = i * 256 + t;
      int kk = c >> 3;
      int dq = (c & 7) ^ (kk & 7);
      async16(Kb + baseq + (size_t)(kt + kk) * 1024 + dq * 8,
              (char*)k_lds + (i * 256 + wave * 64) * 16);
    }
    // stage V^T tile: chunk c -> (d=c>>3, kc=(c&7)^(d&7)); rows of VT are t-contiguous
#pragma unroll
    for (int i = 0; i < 2; ++i) {
      int c = i * 256 + t;
      int d = c >> 3;
      int kc = (c & 7) ^ (d & 7);
      async16(VTb + basev + (size_t)d * 8192 + kt + kc * 8,
              (char*)vt_lds + (i * 256 + wave * 64) * 16);
    }
    __syncthreads();  // staging complete (drains vmcnt)

    // S^T - 16 = K Q^T - 16 (C-init carries the static bound)
    f4 ST[4][2];
#pragma unroll
    for (int mK = 0; mK < 4; ++mK) {
      int key = mK * 16 + l15;
      bh8 ka0 = *(const bh8*)(k_lds + (key * 8 + (quad ^ (key & 7))) * 8);
      bh8 ka1 = *(const bh8*)(k_lds + (key * 8 + ((quad + 4) ^ (key & 7))) * 8);
#pragma unroll
      for (int mi = 0; mi < 2; ++mi) {
        f4 s = (f4){-16.f, -16.f, -16.f, -16.f};
        s = __builtin_amdgcn_mfma_f32_16x16x32_bf16(ka0, qf[mi][0], s, 0, 0, 0);
        s = __builtin_amdgcn_mfma_f32_16x16x32_bf16(ka1, qf[mi][1], s, 0, 0, 0);
        ST[mK][mi] = s;
      }
    }

    // p = exp2(ST); pack to bf16 pairs; redistribute in-register (permlane path).
    bh8 pa[2][2];
#pragma unroll
    for (int mi = 0; mi < 2; ++mi) {
      float lp = 0.f;
      u32 E[4], F[4];
#pragma unroll
      for (int mK = 0; mK < 4; ++mK) {
        float p0 = EXP2(ST[mK][mi][0]);
        float p1 = EXP2(ST[mK][mi][1]);
        float p2 = EXP2(ST[mK][mi][2]);
        float p3 = EXP2(ST[mK][mi][3]);
        lp += (p0 + p1) + (p2 + p3);
        E[mK] = __builtin_amdgcn_perm(__float_as_uint(p1), __float_as_uint(p0), 0x07060302u);
        F[mK] = __builtin_amdgcn_perm(__float_as_uint(p3), __float_as_uint(p2), 0x07060302u);
      }
      l_part[mi] += lp;
#pragma unroll
      for (int ks = 0; ks < 2; ++ks) {
        u32 e0 = E[ks * 2], e1 = E[ks * 2 + 1];
        u32 f0 = F[ks * 2], f1 = F[ks * 2 + 1];
        asm volatile("v_permlane32_swap_b32 %0, %1" : "+v"(e0), "+v"(e1));
        asm volatile("v_permlane16_swap_b32 %0, %1" : "+v"(e0), "+v"(e1));
        asm volatile("v_permlane32_swap_b32 %0, %1" : "+v"(f0), "+v"(f1));
        asm volatile("v_permlane16_swap_b32 %0, %1" : "+v"(f0), "+v"(f1));
        u32x4 w;
        w[0] = e0; w[1] = f0; w[2] = e1; w[3] = f1;
        pa[mi][ks] = __builtin_bit_cast(bh8, w);
      }
    }

    // O += P V
#pragma unroll
    for (int di = 0; di < 4; ++di) {
      int d = di * 16 + l15;
      bh8 vb0 = *(const bh8*)(vt_lds + (d * 8 + (quad ^ (d & 7))) * 8);
      bh8 vb1 = *(const bh8*)(vt_lds + (d * 8 + ((quad + 4) ^ (d & 7))) * 8);
#pragma unroll
      for (int mi = 0; mi < 2; ++mi) {
        f4 o = O[mi][di];
        o = __builtin_amdgcn_mfma_f32_16x16x32_bf16(pa[mi][0], vb0, o, 0, 0, 0);
        o = __builtin_amdgcn_mfma_f32_16x16x32_bf16(pa[mi][1], vb1, o, 0, 0, 0);
        O[mi][di] = o;
      }
    }
  }

  // epilogue: reduce l across quads (lanes sharing l15), broadcast 1/l to O rows, store
#pragma unroll
  for (int mi = 0; mi < 2; ++mi) {
    float l0 = l_part[mi];
    l0 += __shfl_xor(l0, 16);
    l0 += __shfl_xor(l0, 32);
    float rl[4];
#pragma unroll
    for (int r = 0; r < 4; ++r) {
      float lb = __shfl(l0, quad * 4 + r);
      rl[r] = __builtin_amdgcn_rcpf(lb);
    }
#pragma unroll
    for (int di = 0; di < 4; ++di)
#pragma unroll
      for (int r = 0; r < 4; ++r) {
        int row = q0 + wave * 32 + mi * 16 + quad * 4 + r;
        AO[baseq + (size_t)row * 1024 + di * 16 + l15] = f2bf(O[mi][di][r] * rl[r]);
      }
  }
}

// ---------------- launch ----------------
extern "C" void kernel_launch(void* const* d_in, const int* in_sizes, int n_in,
                              void* d_out, int out_size, void* d_ws, size_t ws_size,
                              hipStream_t stream) {
  const float* x  = (const float*)d_in[0];
  const float* Wq = (const float*)d_in[1];
  const float* bq = (const float*)d_in[2];
  const float* Wk = (const float*)d_in[3];
  const float* bk = (const float*)d_in[4];
  const float* Wv = (const float*)d_in[5];
  const float* bv = (const float*)d_in[6];
  const float* Wo = (const float*)d_in[7];
  const float* bo = (const float*)d_in[8];
  float* out = (float*)d_out;

  const int M = 8192, E = 1024;
  const size_t NX = (size_t)M * E;
  const size_t NW = (size_t)E * E;

  short* ws  = (short*)d_ws;
  short* xb  = ws;            // x bf16 [M][E]
  short* wqb = xb + NX;       // weights contiguous: wq, wk, wv, wo
  short* wob = wqb + 3 * NW;
  short* qb  = wob + NW;      // Q bf16 (pre-scaled by log2e/8)
  short* kb  = qb + NX;
  short* vt  = kb + NX;       // V^T bf16 [E][M] (t-contiguous rows)
  short* aob = xb;            // attention output aliases xb (xb dead after QKV GEMM)

  // fused convert: (NX + 4*NW)/4 f4-groups / 256 threads = 12288 blocks exactly
  cvt_all<<<dim3(12288), 256, 0, stream>>>(x, Wq, Wk, Wv, Wo, xb, wqb);

  const float qscale = 0.18033688011112042f;  // log2(e) / sqrt(64)
  gemm_qkv<<<dim3(768), 512, 0, stream>>>(xb, wqb, bq, bk, bv, qb, kb, vt, qscale);

  attn_kernel<<<dim3(16, 64), 256, 0, stream>>>(qb, kb, vt, aob);

  gemm_bt_f32<<<dim3(16, 64), 256, 0, stream>>>(aob, wob, bo, out);
}

// Round 15
// 254.894 us; speedup vs baseline: 1.0659x; 1.0659x over previous
//
#include <hip/hip_runtime.h>

typedef short bh8 __attribute__((ext_vector_type(8)));
typedef short bh4 __attribute__((ext_vector_type(4)));
typedef float f4 __attribute__((ext_vector_type(4)));
typedef unsigned int u32;
typedef u32 u32x2 __attribute__((ext_vector_type(2)));
typedef u32 u32x4 __attribute__((ext_vector_type(4)));

#if __has_builtin(__builtin_amdgcn_exp2f)
#define EXP2(x) __builtin_amdgcn_exp2f(x)
#else
#define EXP2(x) exp2f(x)
#endif

__device__ __forceinline__ short f2bf(float f) {
  unsigned u = __float_as_uint(f);
  u += 0x7FFFu + ((u >> 16) & 1u);
  return (short)(u >> 16);
}

__device__ __forceinline__ void async16(const void* g, void* l) {
  __builtin_amdgcn_global_load_lds((const __attribute__((address_space(1))) void*)g,
                                   (__attribute__((address_space(3))) void*)l, 16, 0, 0);
}

// ---------------- fused fp32 -> bf16 convert: x + Wq,Wk,Wv,Wo in ONE launch ----------------
__global__ void cvt_all(const float* __restrict__ x, const float* __restrict__ Wq,
                        const float* __restrict__ Wk, const float* __restrict__ Wv,
                        const float* __restrict__ Wo, short* __restrict__ xb,
                        short* __restrict__ wqb) {
  int i = blockIdx.x * blockDim.x + threadIdx.x;
  const float* src;
  short* dst;
  int idx;
  if (i < (1 << 21)) {
    src = x; dst = xb; idx = i;
  } else {
    int j = i - (1 << 21);
    int w = j >> 18;
    idx = j & ((1 << 18) - 1);
    src = w == 0 ? Wq : w == 1 ? Wk : w == 2 ? Wv : Wo;
    dst = wqb + ((size_t)w << 20);
  }
  f4 v = *(const f4*)(src + (size_t)idx * 4);
  bh4 o;
  o[0] = f2bf(v[0]); o[1] = f2bf(v[1]); o[2] = f2bf(v[2]); o[3] = f2bf(v[3]);
  *(bh4*)(dst + (size_t)idx * 4) = o;
}

// ---------------- GEMM core (128x128 tile, BK=64, 4 waves, single-buffer 2-barrier) -------
// r15 = r11 EXACT revert (pre-committed rule: T4 counted-vmcnt kernel failed the container
// twice -> implicated; structural sync experiments end). This body is the harness-verified
// 264.6us configuration. C[m][n] = (sum_k A[m][k]*Bw[n][k] + bias)*scale; BROW: bias by row.
template <typename OutT, bool BROW>
__device__ __forceinline__ void gemm_body(const short* __restrict__ A, const short* __restrict__ Bw,
                                          const float* __restrict__ bias, OutT* __restrict__ C,
                                          int m0, int n0, int N, int K, float scale,
                                          short* a_lds, short* b_lds) {
  const int t = threadIdx.x;
  const int lane = t & 63, wave = t >> 6, quad = lane >> 4, l15 = lane & 15;
  const int mw = (wave >> 1) * 64, nw = (wave & 1) * 64;

  f4 acc[4][4];
#pragma unroll
  for (int i = 0; i < 4; ++i)
#pragma unroll
    for (int j = 0; j < 4; ++j) acc[i][j] = (f4){0.f, 0.f, 0.f, 0.f};

  for (int k0 = 0; k0 < K; k0 += 64) {
    __syncthreads();  // prior step's LDS reads done
    // stage A tile [128][64]: chunk c -> (m=c>>3, kq=(c&7)^(m&7)); LDS dest linear c*16
#pragma unroll
    for (int i = 0; i < 4; ++i) {
      int c = i * 256 + t;
      int m = c >> 3;
      int kq = (c & 7) ^ (m & 7);
      async16(A + (size_t)(m0 + m) * K + k0 + kq * 8, (char*)a_lds + c * 16);
    }
#pragma unroll
    for (int i = 0; i < 4; ++i) {
      int c = i * 256 + t;
      int m = c >> 3;
      int kq = (c & 7) ^ (m & 7);
      async16(Bw + (size_t)(n0 + m) * K + k0 + kq * 8, (char*)b_lds + c * 16);
    }
    __syncthreads();  // staging complete (drains vmcnt)

#pragma unroll
    for (int s = 0; s < 2; ++s) {
      bh8 af[4], bfr[4];
#pragma unroll
      for (int ms = 0; ms < 4; ++ms) {
        int m = mw + ms * 16 + l15;
        int pos = m * 8 + ((s * 4 + quad) ^ (m & 7));
        af[ms] = *(const bh8*)(a_lds + pos * 8);
      }
#pragma unroll
      for (int ns = 0; ns < 4; ++ns) {
        int n = nw + ns * 16 + l15;
        int pos = n * 8 + ((s * 4 + quad) ^ (n & 7));
        bfr[ns] = *(const bh8*)(b_lds + pos * 8);
      }
#pragma unroll
      for (int ms = 0; ms < 4; ++ms)
#pragma unroll
        for (int ns = 0; ns < 4; ++ns)
          acc[ms][ns] = __builtin_amdgcn_mfma_f32_16x16x32_bf16(af[ms], bfr[ns], acc[ms][ns], 0, 0, 0);
    }
  }
#pragma unroll
  for (int ns = 0; ns < 4; ++ns) {
    int col = n0 + nw + ns * 16 + l15;
    float bcol = BROW ? 0.f : bias[col & 1023];
#pragma unroll
    for (int ms = 0; ms < 4; ++ms) {
      int row = m0 + mw + ms * 16 + quad * 4;
#pragma unroll
      for (int r = 0; r < 4; ++r) {
        float bv = BROW ? bias[(row + r) & 1023] : bcol;
        float v = (acc[ms][ns][r] + bv) * scale;
        if (sizeof(OutT) == 2)
          ((short*)C)[(size_t)(row + r) * N + col] = f2bf(v);
        else
          ((float*)C)[(size_t)(row + r) * N + col] = v;
      }
    }
  }
}

// fused Q/K/V^T projection: grid 24x64 = 1536 blocks; XCD clustering (bijective).
__global__ void gemm_qkv(const short* __restrict__ xb, const short* __restrict__ W3,
                         const float* __restrict__ bq, const float* __restrict__ bk,
                         const float* __restrict__ bv,
                         short* __restrict__ Qo, short* __restrict__ Ko, short* __restrict__ VTo,
                         float qscale) {
  __shared__ __align__(16) short a_lds[128 * 64];
  __shared__ __align__(16) short b_lds[128 * 64];
  const int linear = blockIdx.y * 24 + blockIdx.x;
  const int xcd = linear & 7;
  const int slot = linear >> 3;          // 0..191
  const int byp = xcd * 8 + slot / 24;   // x row-panel cluster per XCD
  const int rest = slot % 24;
  const int which = rest >> 3;
  const int nx = rest & 7;
  if (which == 2) {
    const short* Wv = W3 + (size_t)2 * 1024 * 1024;
    gemm_body<short, true>(Wv, xb, bv, VTo, nx * 128, byp * 128,
                           8192, 1024, 1.0f, a_lds, b_lds);
  } else {
    const short* Bw = W3 + (size_t)which * 1024 * 1024;
    const float* bias = which == 0 ? bq : bk;
    short* C = which == 0 ? Qo : Ko;
    float scale = which == 0 ? qscale : 1.0f;
    gemm_body<short, false>(xb, Bw, bias, C, byp * 128, nx * 128,
                            1024, 1024, scale, a_lds, b_lds);
  }
}

// ---------------- out-projection (standalone, 128x64 tile, BK=64, 4 waves) ----------------
// 16x64 grid = 1024 blocks = 4 blocks/CU; XCD clustering: each XCD owns 8 A-row-panels
// (2MB) + its Wo slice (2MB) -> L2-resident working set. Standalone (rule #19).
__global__ void gemm_bt_f32(const short* __restrict__ A, const short* __restrict__ Bw,
                            const float* __restrict__ bias, float* __restrict__ C) {
  __shared__ __align__(16) short a_lds[128 * 64];
  __shared__ __align__(16) short b_lds[64 * 64];
  const int t = threadIdx.x;
  const int lane = t & 63, wave = t >> 6, quad = lane >> 4, l15 = lane & 15;
  const int mw = (wave >> 1) * 64, nw = (wave & 1) * 32;
  const int linear = blockIdx.y * 16 + blockIdx.x;
  const int xcd = linear & 7;
  const int slot = linear >> 3;               // 0..127
  const int m0 = (xcd * 8 + (slot >> 4)) * 128;  // A row-panel cluster per XCD
  const int n0 = (slot & 15) * 64;

  f4 acc[4][2];
#pragma unroll
  for (int i = 0; i < 4; ++i)
#pragma unroll
    for (int j = 0; j < 2; ++j) acc[i][j] = (f4){0.f, 0.f, 0.f, 0.f};

  for (int k0 = 0; k0 < 1024; k0 += 64) {
    __syncthreads();
    // stage A tile [128][64]
#pragma unroll
    for (int i = 0; i < 4; ++i) {
      int c = i * 256 + t;
      int m = c >> 3;
      int kq = (c & 7) ^ (m & 7);
      async16(A + (size_t)(m0 + m) * 1024 + k0 + kq * 8, (char*)a_lds + c * 16);
    }
    // stage B tile [64][64]
#pragma unroll
    for (int i = 0; i < 2; ++i) {
      int c = i * 256 + t;
      int m = c >> 3;
      int kq = (c & 7) ^ (m & 7);
      async16(Bw + (size_t)(n0 + m) * 1024 + k0 + kq * 8, (char*)b_lds + c * 16);
    }
    __syncthreads();

#pragma unroll
    for (int s = 0; s < 2; ++s) {
      bh8 af[4], bfr[2];
#pragma unroll
      for (int ms = 0; ms < 4; ++ms) {
        int m = mw + ms * 16 + l15;
        int pos = m * 8 + ((s * 4 + quad) ^ (m & 7));
        af[ms] = *(const bh8*)(a_lds + pos * 8);
      }
#pragma unroll
      for (int ns = 0; ns < 2; ++ns) {
        int n = nw + ns * 16 + l15;
        int pos = n * 8 + ((s * 4 + quad) ^ (n & 7));
        bfr[ns] = *(const bh8*)(b_lds + pos * 8);
      }
#pragma unroll
      for (int ms = 0; ms < 4; ++ms)
#pragma unroll
        for (int ns = 0; ns < 2; ++ns)
          acc[ms][ns] = __builtin_amdgcn_mfma_f32_16x16x32_bf16(af[ms], bfr[ns], acc[ms][ns], 0, 0, 0);
    }
  }
#pragma unroll
  for (int ns = 0; ns < 2; ++ns) {
    int col = n0 + nw + ns * 16 + l15;
    float bcol = bias[col & 1023];
#pragma unroll
    for (int ms = 0; ms < 4; ++ms) {
      int row = m0 + mw + ms * 16 + quad * 4;
#pragma unroll
      for (int r = 0; r < 4; ++r)
        C[(size_t)(row + r) * 1024 + col] = acc[ms][ns][r] + bcol;
    }
  }
}

// ---------------- Flash attention (S^T formulation, static softmax bound) ----------------
// = r9/r11 exactly (85.7us: single-buffer 2-barrier, permlane P-redistribution,
// conflicts 0, XCD head clustering FETCH 24.6MB).
__global__ void attn_kernel(const short* __restrict__ Qb, const short* __restrict__ Kb,
                            const short* __restrict__ VTb, short* __restrict__ AO) {
  __shared__ __align__(16) short k_lds[64 * 64];     // K tile, xor-chunk swizzled [key][d]
  __shared__ __align__(16) short vt_lds[64 * 64];    // V^T tile, xor-chunk swizzled [d][key]
  const int t = threadIdx.x, lane = t & 63, wave = t >> 6, quad = lane >> 4, l15 = lane & 15;
  const int linear = blockIdx.y * 16 + blockIdx.x;
  const int xcd = linear & 7;
  const int slot = linear >> 3;            // 0..127
  const int bh = xcd * 8 + (slot >> 4);    // head clustering: 8 heads per XCD
  const int qx = slot & 15;
  const int b = bh >> 4, h = bh & 15;
  const int q0 = qx * 128;
  const size_t baseq = ((size_t)b * 2048) * 1024 + (size_t)h * 64;
  const size_t basev = ((size_t)h * 64) * 8192 + (size_t)b * 2048;

  // Q fragments in registers (B-operand: n=l15 -> q, k=quad*8+j -> d)
  bh8 qf[2][2];
#pragma unroll
  for (int mi = 0; mi < 2; ++mi)
#pragma unroll
    for (int ks = 0; ks < 2; ++ks)
      qf[mi][ks] = *(const bh8*)(Qb + baseq + (size_t)(q0 + wave * 32 + mi * 16 + l15) * 1024 + ks * 32 + quad * 8);

  f4 O[2][4];
  float l_part[2] = {0.f, 0.f};
#pragma unroll
  for (int mi = 0; mi < 2; ++mi)
#pragma unroll
    for (int di = 0; di < 4; ++di) O[mi][di] = (f4){0.f, 0.f, 0.f, 0.f};

  for (int kt = 0; kt < 2048; kt += 64) {
    __syncthreads();  // prior tile's LDS reads done
    // stage K tile: chunk c -> (kk=c>>3, dq=(c&7)^(kk&7))
#pragma unroll
    for (int i = 0; i < 2; ++i) {
      int c = i * 256 + t;
      int kk = c >> 3;
      int dq = (c & 7) ^ (kk & 7);
      async16(Kb + baseq + (size_t)(kt + kk) * 1024 + dq * 8,
              (char*)k_lds + (i * 256 + wave * 64) * 16);
    }
    // stage V^T tile: chunk c -> (d=c>>3, kc=(c&7)^(d&7)); rows of VT are t-contiguous
#pragma unroll
    for (int i = 0; i < 2; ++i) {
      int c = i * 256 + t;
      int d = c >> 3;
      int kc = (c & 7) ^ (d & 7);
      async16(VTb + basev + (size_t)d * 8192 + kt + kc * 8,
              (char*)vt_lds + (i * 256 + wave * 64) * 16);
    }
    __syncthreads();  // staging complete (drains vmcnt)

    // S^T - 16 = K Q^T - 16 (C-init carries the static bound)
    f4 ST[4][2];
#pragma unroll
    for (int mK = 0; mK < 4; ++mK) {
      int key = mK * 16 + l15;
      bh8 ka0 = *(const bh8*)(k_lds + (key * 8 + (quad ^ (key & 7))) * 8);
      bh8 ka1 = *(const bh8*)(k_lds + (key * 8 + ((quad + 4) ^ (key & 7))) * 8);
#pragma unroll
      for (int mi = 0; mi < 2; ++mi) {
        f4 s = (f4){-16.f, -16.f, -16.f, -16.f};
        s = __builtin_amdgcn_mfma_f32_16x16x32_bf16(ka0, qf[mi][0], s, 0, 0, 0);
        s = __builtin_amdgcn_mfma_f32_16x16x32_bf16(ka1, qf[mi][1], s, 0, 0, 0);
        ST[mK][mi] = s;
      }
    }

    // p = exp2(ST); pack to bf16 pairs; redistribute in-register (permlane path).
    bh8 pa[2][2];
#pragma unroll
    for (int mi = 0; mi < 2; ++mi) {
      float lp = 0.f;
      u32 E[4], F[4];
#pragma unroll
      for (int mK = 0; mK < 4; ++mK) {
        float p0 = EXP2(ST[mK][mi][0]);
        float p1 = EXP2(ST[mK][mi][1]);
        float p2 = EXP2(ST[mK][mi][2]);
        float p3 = EXP2(ST[mK][mi][3]);
        lp += (p0 + p1) + (p2 + p3);
        E[mK] = __builtin_amdgcn_perm(__float_as_uint(p1), __float_as_uint(p0), 0x07060302u);
        F[mK] = __builtin_amdgcn_perm(__float_as_uint(p3), __float_as_uint(p2), 0x07060302u);
      }
      l_part[mi] += lp;
#pragma unroll
      for (int ks = 0; ks < 2; ++ks) {
        u32 e0 = E[ks * 2], e1 = E[ks * 2 + 1];
        u32 f0 = F[ks * 2], f1 = F[ks * 2 + 1];
        asm volatile("v_permlane32_swap_b32 %0, %1" : "+v"(e0), "+v"(e1));
        asm volatile("v_permlane16_swap_b32 %0, %1" : "+v"(e0), "+v"(e1));
        asm volatile("v_permlane32_swap_b32 %0, %1" : "+v"(f0), "+v"(f1));
        asm volatile("v_permlane16_swap_b32 %0, %1" : "+v"(f0), "+v"(f1));
        u32x4 w;
        w[0] = e0; w[1] = f0; w[2] = e1; w[3] = f1;
        pa[mi][ks] = __builtin_bit_cast(bh8, w);
      }
    }

    // O += P V
#pragma unroll
    for (int di = 0; di < 4; ++di) {
      int d = di * 16 + l15;
      bh8 vb0 = *(const bh8*)(vt_lds + (d * 8 + (quad ^ (d & 7))) * 8);
      bh8 vb1 = *(const bh8*)(vt_lds + (d * 8 + ((quad + 4) ^ (d & 7))) * 8);
#pragma unroll
      for (int mi = 0; mi < 2; ++mi) {
        f4 o = O[mi][di];
        o = __builtin_amdgcn_mfma_f32_16x16x32_bf16(pa[mi][0], vb0, o, 0, 0, 0);
        o = __builtin_amdgcn_mfma_f32_16x16x32_bf16(pa[mi][1], vb1, o, 0, 0, 0);
        O[mi][di] = o;
      }
    }
  }

  // epilogue: reduce l across quads (lanes sharing l15), broadcast 1/l to O rows, store
#pragma unroll
  for (int mi = 0; mi < 2; ++mi) {
    float l0 = l_part[mi];
    l0 += __shfl_xor(l0, 16);
    l0 += __shfl_xor(l0, 32);
    float rl[4];
#pragma unroll
    for (int r = 0; r < 4; ++r) {
      float lb = __shfl(l0, quad * 4 + r);
      rl[r] = __builtin_amdgcn_rcpf(lb);
    }
#pragma unroll
    for (int di = 0; di < 4; ++di)
#pragma unroll
      for (int r = 0; r < 4; ++r) {
        int row = q0 + wave * 32 + mi * 16 + quad * 4 + r;
        AO[baseq + (size_t)row * 1024 + di * 16 + l15] = f2bf(O[mi][di][r] * rl[r]);
      }
  }
}

// ---------------- launch ----------------
extern "C" void kernel_launch(void* const* d_in, const int* in_sizes, int n_in,
                              void* d_out, int out_size, void* d_ws, size_t ws_size,
                              hipStream_t stream) {
  const float* x  = (const float*)d_in[0];
  const float* Wq = (const float*)d_in[1];
  const float* bq = (const float*)d_in[2];
  const float* Wk = (const float*)d_in[3];
  const float* bk = (const float*)d_in[4];
  const float* Wv = (const float*)d_in[5];
  const float* bv = (const float*)d_in[6];
  const float* Wo = (const float*)d_in[7];
  const float* bo = (const float*)d_in[8];
  float* out = (float*)d_out;

  const int M = 8192, E = 1024;
  const size_t NX = (size_t)M * E;
  const size_t NW = (size_t)E * E;

  short* ws  = (short*)d_ws;
  short* xb  = ws;            // x bf16 [M][E]
  short* wqb = xb + NX;       // weights contiguous: wq, wk, wv, wo
  short* wob = wqb + 3 * NW;
  short* qb  = wob + NW;      // Q bf16 (pre-scaled by log2e/8)
  short* kb  = qb + NX;
  short* vt  = kb + NX;       // V^T bf16 [E][M] (t-contiguous rows)
  short* aob = xb;            // attention output aliases xb (xb dead after QKV GEMM)

  // fused convert: (NX + 4*NW)/4 f4-groups / 256 threads = 12288 blocks exactly
  cvt_all<<<dim3(12288), 256, 0, stream>>>(x, Wq, Wk, Wv, Wo, xb, wqb);

  const float qscale = 0.18033688011112042f;  // log2(e) / sqrt(64)
  gemm_qkv<<<dim3(24, 64), 256, 0, stream>>>(xb, wqb, bq, bk, bv, qb, kb, vt, qscale);

  attn_kernel<<<dim3(16, 64), 256, 0, stream>>>(qb, kb, vt, aob);

  gemm_bt_f32<<<dim3(16, 64), 256, 0, stream>>>(aob, wob, bo, out);
}